// Round 1
// baseline (490.699 us; speedup 1.0000x reference)
//
#include <hip/hip_runtime.h>
#include <hip/hip_bf16.h>

#define B_ 8
#define C_ 256
#define N_ 4096
#define S_ 64

typedef __attribute__((ext_vector_type(8))) short short8;
typedef __attribute__((ext_vector_type(4))) short short4v;
typedef __attribute__((ext_vector_type(4))) float f32x4;

__device__ __forceinline__ short f2b(float f) {
  unsigned u = __float_as_uint(f);
  unsigned r = (u + 0x7FFFu + ((u >> 16) & 1u)) >> 16;
  return (short)(r & 0xFFFFu);
}

__device__ __forceinline__ short8 ld8f_cvt(const float* __restrict__ p) {
  short8 r;
#pragma unroll
  for (int j = 0; j < 8; j++) r[j] = f2b(p[j]);
  return r;
}

// K0: transpose+convert x (f32 [b][c][n]) -> xt (bf16 [b][n][c])
__global__ __launch_bounds__(256) void k0_transpose(const float* __restrict__ x,
                                                    short* __restrict__ xt) {
  __shared__ float tile[64][65];
  int b = blockIdx.z, c0 = blockIdx.y * 64, n0 = blockIdx.x * 64;
  int tn = threadIdx.x & 63, tc = threadIdx.x >> 6;
  const float* xb = x + ((size_t)b * C_ + c0) * N_ + n0;
#pragma unroll
  for (int i = 0; i < 16; i++) {
    int c = tc * 16 + i;
    tile[c][tn] = xb[(size_t)c * N_ + tn];
  }
  __syncthreads();
  short* xtb = xt + ((size_t)b * N_ + n0) * C_ + c0;
#pragma unroll
  for (int i = 0; i < 16; i++) {
    int n = tc * 16 + i;
    xtb[(size_t)n * C_ + tn] = f2b(tile[tn][n]);
  }
}

// K1: xqk = W_qk*x (f32), write Qt bf16 [b][n][s]; then k2c on concat(xqk, gather)
// + softmax over s -> Kt bf16 [b][n][s].  block (64 n, 4 s-groups); W loads wave-uniform.
__global__ __launch_bounds__(256) void k1_qk(const float* __restrict__ x,
    const float* __restrict__ Wqk, const float* __restrict__ Wk2c,
    const int* __restrict__ idx, short* __restrict__ Qt, short* __restrict__ Kt) {
  int b = blockIdx.y, n0 = blockIdx.x * 64;
  int tn = threadIdx.x;
  int sg = __builtin_amdgcn_readfirstlane(threadIdx.y);
  const float* xb = x + (size_t)b * C_ * N_ + n0 + tn;
  float acc[16];
#pragma unroll
  for (int i = 0; i < 16; i++) acc[i] = 0.f;
  for (int c = 0; c < C_; c += 4) {
    float x0 = xb[(size_t)c * N_];
    float x1 = xb[(size_t)(c + 1) * N_];
    float x2 = xb[(size_t)(c + 2) * N_];
    float x3 = xb[(size_t)(c + 3) * N_];
#pragma unroll
    for (int i = 0; i < 16; i++) {
      const float* wr = Wqk + (sg * 16 + i) * C_ + c;
      acc[i] += wr[0] * x0 + wr[1] * x1 + wr[2] * x2 + wr[3] * x3;
    }
  }
  __shared__ float q_lds[64][65];
  __shared__ float red[4][64];
#pragma unroll
  for (int i = 0; i < 16; i++) q_lds[sg * 16 + i][tn] = acc[i];
  {
    short* qrow = Qt + ((size_t)b * N_ + n0 + tn) * S_ + sg * 16;
#pragma unroll
    for (int i = 0; i < 16; i++) qrow[i] = f2b(acc[i]);
  }
  __syncthreads();
  float acc2[16];
#pragma unroll
  for (int i = 0; i < 16; i++) acc2[i] = 0.f;
  for (int h = 0; h < 64; h += 4) {
    float q0 = q_lds[h][tn], q1 = q_lds[h + 1][tn];
    float q2 = q_lds[h + 2][tn], q3 = q_lds[h + 3][tn];
#pragma unroll
    for (int i = 0; i < 16; i++) {
      const float* wr = Wk2c + (sg * 16 + i) * 128 + h;
      acc2[i] += wr[0] * q0 + wr[1] * q1 + wr[2] * q2 + wr[3] * q3;
    }
  }
  for (int h = 0; h < 64; h += 4) {
    float g0 = xb[(size_t)idx[h] * N_];
    float g1 = xb[(size_t)idx[h + 1] * N_];
    float g2 = xb[(size_t)idx[h + 2] * N_];
    float g3 = xb[(size_t)idx[h + 3] * N_];
#pragma unroll
    for (int i = 0; i < 16; i++) {
      const float* wr = Wk2c + (sg * 16 + i) * 128 + 64 + h;
      acc2[i] += wr[0] * g0 + wr[1] * g1 + wr[2] * g2 + wr[3] * g3;
    }
  }
  float pm = acc2[0];
#pragma unroll
  for (int i = 1; i < 16; i++) pm = fmaxf(pm, acc2[i]);
  red[sg][tn] = pm;
  __syncthreads();
  float mx = fmaxf(fmaxf(red[0][tn], red[1][tn]), fmaxf(red[2][tn], red[3][tn]));
  float ps = 0.f;
  float ex[16];
#pragma unroll
  for (int i = 0; i < 16; i++) { ex[i] = __expf(acc2[i] - mx); ps += ex[i]; }
  __syncthreads();
  red[sg][tn] = ps;
  __syncthreads();
  float inv = 1.f / (red[0][tn] + red[1][tn] + red[2][tn] + red[3][tn]);
  short* krow = Kt + ((size_t)b * N_ + n0 + tn) * S_ + sg * 16;
#pragma unroll
  for (int i = 0; i < 16; i++) krow[i] = f2b(ex[i] * inv);
}

// K2: V = W_v * x + b_v  -> bf16 [b][c][n], MFMA, B-frags from xt.
__global__ __launch_bounds__(256) void k2_xv(const float* __restrict__ Wv,
    const float* __restrict__ bv, const short* __restrict__ xt, short* __restrict__ V) {
  int b = blockIdx.y, n0 = blockIdx.x * 64;
  int lane = threadIdx.x & 63, w = threadIdx.x >> 6;
  int lr = lane & 15, lg = lane >> 4;
  f32x4 acc[4][4];
#pragma unroll
  for (int i = 0; i < 4; i++)
#pragma unroll
    for (int j = 0; j < 4; j++) acc[i][j] = {0.f, 0.f, 0.f, 0.f};
  const short* xtb = xt + ((size_t)b * N_ + n0) * C_;
#pragma unroll 1
  for (int ks = 0; ks < 8; ks++) {
    int kb = ks * 32 + lg * 8;
    short8 bfrag[4];
#pragma unroll
    for (int ns = 0; ns < 4; ns++)
      bfrag[ns] = *(const short8*)(xtb + (size_t)(ns * 16 + lr) * C_ + kb);
#pragma unroll
    for (int os = 0; os < 4; os++) {
      short8 af = ld8f_cvt(Wv + (size_t)(w * 64 + os * 16 + lr) * C_ + kb);
#pragma unroll
      for (int ns = 0; ns < 4; ns++)
        acc[os][ns] = __builtin_amdgcn_mfma_f32_16x16x32_bf16(af, bfrag[ns], acc[os][ns], 0, 0, 0);
    }
  }
  short* Vb = V + (size_t)b * C_ * N_ + n0;
#pragma unroll
  for (int os = 0; os < 4; os++) {
#pragma unroll
    for (int r = 0; r < 4; r++) {
      int o = w * 64 + os * 16 + lg * 4 + r;
      float bvo = bv[o];
#pragma unroll
      for (int ns = 0; ns < 4; ns++)
        Vb[(size_t)o * N_ + ns * 16 + lr] = f2b(acc[os][ns][r] + bvo);
    }
  }
}

// K3: inv_rse[b][n] = 1 / sum_m exp(energy[b,n,m])   (no max-shift: |e| <= ~5.5)
__global__ __launch_bounds__(256) void k3_rse(const short* __restrict__ Qt,
    const short* __restrict__ Kt, float* __restrict__ inv_rse) {
  int b = blockIdx.y, n0 = blockIdx.x * 64;
  int lane = threadIdx.x & 63, w = threadIdx.x >> 6;
  int lr = lane & 15, lg = lane >> 4;
  const short* Qb = Qt + (size_t)b * N_ * S_;
  const short* Kb = Kt + (size_t)b * N_ * S_;
  short8 qf[2];
#pragma unroll
  for (int ks = 0; ks < 2; ks++)
    qf[ks] = *(const short8*)(Qb + (size_t)(n0 + w * 16 + lr) * S_ + ks * 32 + lg * 8);
  float rs[4] = {0.f, 0.f, 0.f, 0.f};
#pragma unroll 1
  for (int m0 = 0; m0 < N_; m0 += 64) {
#pragma unroll
    for (int ms = 0; ms < 4; ms++) {
      f32x4 e = {0.f, 0.f, 0.f, 0.f};
#pragma unroll
      for (int ks = 0; ks < 2; ks++) {
        short8 kf = *(const short8*)(Kb + (size_t)(m0 + ms * 16 + lr) * S_ + ks * 32 + lg * 8);
        e = __builtin_amdgcn_mfma_f32_16x16x32_bf16(qf[ks], kf, e, 0, 0, 0);
      }
#pragma unroll
      for (int r = 0; r < 4; r++) rs[r] += __expf(e[r]);
    }
  }
#pragma unroll
  for (int off = 1; off < 16; off <<= 1)
#pragma unroll
    for (int r = 0; r < 4; r++) rs[r] += __shfl_xor(rs[r], off, 64);
  if (lr == 0) {
#pragma unroll
    for (int r = 0; r < 4; r++)
      inv_rse[(size_t)b * N_ + n0 + w * 16 + lg * 4 + r] = 1.f / rs[r];
  }
}

// K4: fused energy->att->PV per (b, 64-wide m tile). Output xrp bf16 [b][m][c].
__global__ __launch_bounds__(256) void k4_att(const short* __restrict__ Qt,
    const short* __restrict__ Kt, const short* __restrict__ V,
    const float* __restrict__ inv_rse, short* __restrict__ xrp) {
  int b = blockIdx.y, m0 = blockIdx.x * 64;
  int lane = threadIdx.x & 63, w = threadIdx.x >> 6;
  int lr = lane & 15, lg = lane >> 4;
  __shared__ short att[64][72];   // [m][n], 144B rows (16B-aligned, even bank spread)
  __shared__ float cs_red[4][64];
  const short* Qb = Qt + (size_t)b * N_ * S_;
  const short* Kb = Kt + (size_t)b * N_ * S_;
  const short* Vb = V + (size_t)b * C_ * N_;
  const float* irse = inv_rse + (size_t)b * N_;
  short8 kfrag[4][2];
#pragma unroll
  for (int ms = 0; ms < 4; ms++)
#pragma unroll
    for (int ks = 0; ks < 2; ks++)
      kfrag[ms][ks] = *(const short8*)(Kb + (size_t)(m0 + ms * 16 + lr) * S_ + ks * 32 + lg * 8);
  f32x4 P[4][4];
#pragma unroll
  for (int i = 0; i < 4; i++)
#pragma unroll
    for (int j = 0; j < 4; j++) P[i][j] = {0.f, 0.f, 0.f, 0.f};
  float csum[4] = {0.f, 0.f, 0.f, 0.f};
#pragma unroll 1
  for (int n0 = 0; n0 < N_; n0 += 64) {
    short8 qf[2];
#pragma unroll
    for (int ks = 0; ks < 2; ks++)
      qf[ks] = *(const short8*)(Qb + (size_t)(n0 + w * 16 + lr) * S_ + ks * 32 + lg * 8);
    f32x4 e[4];
#pragma unroll
    for (int ms = 0; ms < 4; ms++) e[ms] = {0.f, 0.f, 0.f, 0.f};
#pragma unroll
    for (int ms = 0; ms < 4; ms++)
#pragma unroll
      for (int ks = 0; ks < 2; ks++)
        e[ms] = __builtin_amdgcn_mfma_f32_16x16x32_bf16(qf[ks], kfrag[ms][ks], e[ms], 0, 0, 0);
    float ir[4];
#pragma unroll
    for (int r = 0; r < 4; r++) ir[r] = irse[n0 + w * 16 + lg * 4 + r];
    __syncthreads();   // previous P-phase att reads done before overwrite
#pragma unroll
    for (int ms = 0; ms < 4; ms++) {
      short4v pk;
#pragma unroll
      for (int r = 0; r < 4; r++) {
        float a = __expf(e[ms][r]) * ir[r];
        csum[ms] += a;
        pk[r] = f2b(a);
      }
      *(short4v*)(&att[ms * 16 + lr][w * 16 + lg * 4]) = pk;
    }
    __syncthreads();
#pragma unroll
    for (int ks = 0; ks < 2; ks++) {
      short8 bfr[4];
#pragma unroll
      for (int ms = 0; ms < 4; ms++)
        bfr[ms] = *(const short8*)(&att[ms * 16 + lr][ks * 32 + lg * 8]);
#pragma unroll
      for (int cs = 0; cs < 4; cs++) {
        short8 af = *(const short8*)(Vb + (size_t)(w * 64 + cs * 16 + lr) * N_ + n0 + ks * 32 + lg * 8);
#pragma unroll
        for (int ms = 0; ms < 4; ms++)
          P[cs][ms] = __builtin_amdgcn_mfma_f32_16x16x32_bf16(af, bfr[ms], P[cs][ms], 0, 0, 0);
      }
    }
  }
#pragma unroll
  for (int off = 16; off < 64; off <<= 1)
#pragma unroll
    for (int ms = 0; ms < 4; ms++) csum[ms] += __shfl_xor(csum[ms], off, 64);
  if (lg == 0) {
#pragma unroll
    for (int ms = 0; ms < 4; ms++) cs_red[w][ms * 16 + lr] = csum[ms];
  }
  __syncthreads();
  float cinv[4];
#pragma unroll
  for (int ms = 0; ms < 4; ms++) {
    int m = ms * 16 + lr;
    cinv[ms] = 1.f / (1e-9f + cs_red[0][m] + cs_red[1][m] + cs_red[2][m] + cs_red[3][m]);
  }
  short* xb = xrp + ((size_t)b * N_ + m0) * C_;
#pragma unroll
  for (int cs = 0; cs < 4; cs++)
#pragma unroll
    for (int ms = 0; ms < 4; ms++) {
      short4v pk;
#pragma unroll
      for (int r = 0; r < 4; r++) pk[r] = f2b(P[cs][ms][r] * cinv[ms]);
      *(short4v*)(xb + (size_t)(ms * 16 + lr) * C_ + w * 64 + cs * 16 + lg * 4) = pk;
    }
}

// K5: out = x + relu(BN(W_t * x_r + b_t))
__global__ __launch_bounds__(256) void k5_out(const float* __restrict__ Wt,
    const float* __restrict__ bt, const float* __restrict__ gamma,
    const float* __restrict__ beta, const float* __restrict__ mean,
    const float* __restrict__ var, const short* __restrict__ xrp,
    const float* __restrict__ x, float* __restrict__ out) {
  int b = blockIdx.y, m0 = blockIdx.x * 64;
  int lane = threadIdx.x & 63, w = threadIdx.x >> 6;
  int lr = lane & 15, lg = lane >> 4;
  f32x4 acc[4][4];
#pragma unroll
  for (int i = 0; i < 4; i++)
#pragma unroll
    for (int j = 0; j < 4; j++) acc[i][j] = {0.f, 0.f, 0.f, 0.f};
  const short* xrb = xrp + ((size_t)b * N_ + m0) * C_;
#pragma unroll 1
  for (int ks = 0; ks < 8; ks++) {
    int kb = ks * 32 + lg * 8;
    short8 bfr[4];
#pragma unroll
    for (int ms = 0; ms < 4; ms++)
      bfr[ms] = *(const short8*)(xrb + (size_t)(ms * 16 + lr) * C_ + kb);
#pragma unroll
    for (int os = 0; os < 4; os++) {
      short8 af = ld8f_cvt(Wt + (size_t)(w * 64 + os * 16 + lr) * C_ + kb);
#pragma unroll
      for (int ms = 0; ms < 4; ms++)
        acc[os][ms] = __builtin_amdgcn_mfma_f32_16x16x32_bf16(af, bfr[ms], acc[os][ms], 0, 0, 0);
    }
  }
  const float* xb = x + (size_t)b * C_ * N_ + m0;
  float* ob = out + (size_t)b * C_ * N_ + m0;
#pragma unroll
  for (int os = 0; os < 4; os++)
#pragma unroll
    for (int r = 0; r < 4; r++) {
      int o = w * 64 + os * 16 + lg * 4 + r;
      float bb = bt[o];
      float iv = gamma[o] * rsqrtf(var[o] + 1e-5f);
      float mn = mean[o], be = beta[o];
#pragma unroll
      for (int ms = 0; ms < 4; ms++) {
        int m = ms * 16 + lr;
        float v = (acc[os][ms][r] + bb - mn) * iv + be;
        v = fmaxf(v, 0.f);
        ob[(size_t)o * N_ + m] = xb[(size_t)o * N_ + m] + v;
      }
    }
}

extern "C" void kernel_launch(void* const* d_in, const int* in_sizes, int n_in,
                              void* d_out, int out_size, void* d_ws, size_t ws_size,
                              hipStream_t stream) {
  const float* x     = (const float*)d_in[0];
  const float* Wqk   = (const float*)d_in[1];
  const float* Wk2c  = (const float*)d_in[2];
  const float* Wv    = (const float*)d_in[3];
  const float* bv    = (const float*)d_in[4];
  const float* Wt    = (const float*)d_in[5];
  const float* bt    = (const float*)d_in[6];
  const float* gamma = (const float*)d_in[7];
  const float* beta  = (const float*)d_in[8];
  const float* mean  = (const float*)d_in[9];
  const float* var   = (const float*)d_in[10];
  const int*   idx   = (const int*)d_in[11];
  float* out = (float*)d_out;

  char* ws = (char*)d_ws;
  size_t off = 0;
  auto alloc = [&](size_t bytes) -> void* {
    void* p = ws + off;
    off = (off + bytes + 255) & ~(size_t)255;
    return p;
  };
  short* xt   = (short*)alloc((size_t)B_ * N_ * C_ * 2);
  short* Qt   = (short*)alloc((size_t)B_ * N_ * S_ * 2);
  short* Kt   = (short*)alloc((size_t)B_ * N_ * S_ * 2);
  short* V    = (short*)alloc((size_t)B_ * C_ * N_ * 2);
  float* irse = (float*)alloc((size_t)B_ * N_ * 4);
  short* xrp  = (short*)alloc((size_t)B_ * N_ * C_ * 2);

  k0_transpose<<<dim3(N_ / 64, C_ / 64, B_), 256, 0, stream>>>(x, xt);
  k1_qk<<<dim3(N_ / 64, B_), dim3(64, 4), 0, stream>>>(x, Wqk, Wk2c, idx, Qt, Kt);
  k2_xv<<<dim3(N_ / 64, B_), 256, 0, stream>>>(Wv, bv, xt, V);
  k3_rse<<<dim3(N_ / 64, B_), 256, 0, stream>>>(Qt, Kt, irse);
  k4_att<<<dim3(N_ / 64, B_), 256, 0, stream>>>(Qt, Kt, V, irse, xrp);
  k5_out<<<dim3(N_ / 64, B_), 256, 0, stream>>>(Wt, bt, gamma, beta, mean, var, xrp, x, out);
}

// Round 2
// 476.503 us; speedup vs baseline: 1.0298x; 1.0298x over previous
//
#include <hip/hip_runtime.h>
#include <hip/hip_bf16.h>

#define B_ 8
#define C_ 256
#define N_ 4096
#define S_ 64
#define LOG2E 1.4426950408889634f

typedef __attribute__((ext_vector_type(8))) short short8;
typedef __attribute__((ext_vector_type(4))) short short4v;
typedef __attribute__((ext_vector_type(4))) float f32x4;

__device__ __forceinline__ short f2b(float f) {
  unsigned u = __float_as_uint(f);
  unsigned r = (u + 0x7FFFu + ((u >> 16) & 1u)) >> 16;
  return (short)(r & 0xFFFFu);
}

// pack two f32 -> two bf16 in one instr (lo -> [15:0], hi -> [31:16])
__device__ __forceinline__ int cvtpk(float lo, float hi) {
  int r;
  asm("v_cvt_pk_bf16_f32 %0, %1, %2" : "=v"(r) : "v"(lo), "v"(hi));
  return r;
}

// K0: transpose+convert x (f32 [b][c][n]) -> xt (bf16 [b][n][c])
__global__ __launch_bounds__(256) void k0_transpose(const float* __restrict__ x,
                                                    short* __restrict__ xt) {
  __shared__ float tile[64][65];
  int b = blockIdx.z, c0 = blockIdx.y * 64, n0 = blockIdx.x * 64;
  int tn = threadIdx.x & 63, tc = threadIdx.x >> 6;
  const float* xb = x + ((size_t)b * C_ + c0) * N_ + n0;
#pragma unroll
  for (int i = 0; i < 16; i++) {
    int c = tc * 16 + i;
    tile[c][tn] = xb[(size_t)c * N_ + tn];
  }
  __syncthreads();
  short* xtb = xt + ((size_t)b * N_ + n0) * C_ + c0;
#pragma unroll
  for (int i = 0; i < 16; i++) {
    int n = tc * 16 + i;
    xtb[(size_t)n * C_ + tn] = f2b(tile[tn][n]);
  }
}

// KW: one-shot f32->bf16 convert of W_v and W_t (65536 elems each)
__global__ __launch_bounds__(256) void kw_conv(const float* __restrict__ Wv,
    const float* __restrict__ Wt, short* __restrict__ Wvb, short* __restrict__ Wtb) {
  int t = blockIdx.x * 256 + threadIdx.x;           // 16384 threads
  const float* src = (t < 8192) ? Wv : Wt;
  short* dst = (t < 8192) ? Wvb : Wtb;
  int i = (t & 8191) * 8;
  short8 o;
#pragma unroll
  for (int j = 0; j < 8; j++) o[j] = f2b(src[i + j]);
  *(short8*)(dst + i) = o;
}

// K1: xqk = W_qk*x (f32); Qt bf16 [b][n][s] PRE-SCALED by log2(e); Kt = softmax(k2c) bf16.
__global__ __launch_bounds__(256) void k1_qk(const float* __restrict__ x,
    const float* __restrict__ Wqk, const float* __restrict__ Wk2c,
    const int* __restrict__ idx, short* __restrict__ Qt, short* __restrict__ Kt) {
  int b = blockIdx.y, n0 = blockIdx.x * 64;
  int tn = threadIdx.x;
  int sg = __builtin_amdgcn_readfirstlane(threadIdx.y);
  const float* xb = x + (size_t)b * C_ * N_ + n0 + tn;
  float acc[16];
#pragma unroll
  for (int i = 0; i < 16; i++) acc[i] = 0.f;
  for (int c = 0; c < C_; c += 4) {
    float x0 = xb[(size_t)c * N_];
    float x1 = xb[(size_t)(c + 1) * N_];
    float x2 = xb[(size_t)(c + 2) * N_];
    float x3 = xb[(size_t)(c + 3) * N_];
#pragma unroll
    for (int i = 0; i < 16; i++) {
      const float* wr = Wqk + (sg * 16 + i) * C_ + c;
      acc[i] += wr[0] * x0 + wr[1] * x1 + wr[2] * x2 + wr[3] * x3;
    }
  }
  __shared__ float q_lds[64][65];
  __shared__ float red[4][64];
#pragma unroll
  for (int i = 0; i < 16; i++) q_lds[sg * 16 + i][tn] = acc[i];
  {
    short* qrow = Qt + ((size_t)b * N_ + n0 + tn) * S_ + sg * 16;
#pragma unroll
    for (int i = 0; i < 16; i++) qrow[i] = f2b(acc[i] * LOG2E);
  }
  __syncthreads();
  float acc2[16];
#pragma unroll
  for (int i = 0; i < 16; i++) acc2[i] = 0.f;
  for (int h = 0; h < 64; h += 4) {
    float q0 = q_lds[h][tn], q1 = q_lds[h + 1][tn];
    float q2 = q_lds[h + 2][tn], q3 = q_lds[h + 3][tn];
#pragma unroll
    for (int i = 0; i < 16; i++) {
      const float* wr = Wk2c + (sg * 16 + i) * 128 + h;
      acc2[i] += wr[0] * q0 + wr[1] * q1 + wr[2] * q2 + wr[3] * q3;
    }
  }
  for (int h = 0; h < 64; h += 4) {
    float g0 = xb[(size_t)idx[h] * N_];
    float g1 = xb[(size_t)idx[h + 1] * N_];
    float g2 = xb[(size_t)idx[h + 2] * N_];
    float g3 = xb[(size_t)idx[h + 3] * N_];
#pragma unroll
    for (int i = 0; i < 16; i++) {
      const float* wr = Wk2c + (sg * 16 + i) * 128 + 64 + h;
      acc2[i] += wr[0] * g0 + wr[1] * g1 + wr[2] * g2 + wr[3] * g3;
    }
  }
  float pm = acc2[0];
#pragma unroll
  for (int i = 1; i < 16; i++) pm = fmaxf(pm, acc2[i]);
  red[sg][tn] = pm;
  __syncthreads();
  float mx = fmaxf(fmaxf(red[0][tn], red[1][tn]), fmaxf(red[2][tn], red[3][tn]));
  float ps = 0.f;
  float ex[16];
#pragma unroll
  for (int i = 0; i < 16; i++) { ex[i] = __expf(acc2[i] - mx); ps += ex[i]; }
  __syncthreads();
  red[sg][tn] = ps;
  __syncthreads();
  float inv = 1.f / (red[0][tn] + red[1][tn] + red[2][tn] + red[3][tn]);
  short* krow = Kt + ((size_t)b * N_ + n0 + tn) * S_ + sg * 16;
#pragma unroll
  for (int i = 0; i < 16; i++) krow[i] = f2b(ex[i] * inv);
}

// K2: V = W_v * x + b_v -> bf16 PANEL-TILED Vp[b][n/64][c][64]
__global__ __launch_bounds__(256) void k2_xv(const short* __restrict__ Wvb,
    const float* __restrict__ bv, const short* __restrict__ xt, short* __restrict__ Vp) {
  int b = blockIdx.y, nblk = blockIdx.x, n0 = nblk * 64;
  int lane = threadIdx.x & 63, w = threadIdx.x >> 6;
  int lr = lane & 15, lg = lane >> 4;
  f32x4 acc[4][4];
#pragma unroll
  for (int i = 0; i < 4; i++)
#pragma unroll
    for (int j = 0; j < 4; j++) acc[i][j] = {0.f, 0.f, 0.f, 0.f};
  const short* xtb = xt + ((size_t)b * N_ + n0) * C_;
#pragma unroll 1
  for (int ks = 0; ks < 8; ks++) {
    int kb = ks * 32 + lg * 8;
    short8 bfrag[4];
#pragma unroll
    for (int ns = 0; ns < 4; ns++)
      bfrag[ns] = *(const short8*)(xtb + (size_t)(ns * 16 + lr) * C_ + kb);
#pragma unroll
    for (int os = 0; os < 4; os++) {
      short8 af = *(const short8*)(Wvb + (size_t)(w * 64 + os * 16 + lr) * C_ + kb);
#pragma unroll
      for (int ns = 0; ns < 4; ns++)
        acc[os][ns] = __builtin_amdgcn_mfma_f32_16x16x32_bf16(af, bfrag[ns], acc[os][ns], 0, 0, 0);
    }
  }
  short* Vb = Vp + ((size_t)b * 64 + nblk) * (C_ * 64);
#pragma unroll
  for (int os = 0; os < 4; os++) {
#pragma unroll
    for (int r = 0; r < 4; r++) {
      int o = w * 64 + os * 16 + lg * 4 + r;
      float bvo = bv[o];
#pragma unroll
      for (int ns = 0; ns < 4; ns++)
        Vb[(size_t)o * 64 + ns * 16 + lr] = f2b(acc[os][ns][r] + bvo);
    }
  }
}

// K3: inv_rse[b][n] = 1 / sum_m exp2(e2[n,m])  (Qt pre-scaled, so exp2 == exp of energy)
__global__ __launch_bounds__(256) void k3_rse(const short* __restrict__ Qt,
    const short* __restrict__ Kt, float* __restrict__ inv_rse) {
  int b = blockIdx.y, n0 = blockIdx.x * 64;
  int lane = threadIdx.x & 63, w = threadIdx.x >> 6;
  int lr = lane & 15, lg = lane >> 4;
  const short* Qb = Qt + (size_t)b * N_ * S_;
  const short* Kb = Kt + (size_t)b * N_ * S_;
  short8 qf[2];
#pragma unroll
  for (int ks = 0; ks < 2; ks++)
    qf[ks] = *(const short8*)(Qb + (size_t)(n0 + w * 16 + lr) * S_ + ks * 32 + lg * 8);
  // prefetch m-tile 0
  short8 kc[4][2], kn[4][2];
#pragma unroll
  for (int ms = 0; ms < 4; ms++)
#pragma unroll
    for (int ks = 0; ks < 2; ks++)
      kc[ms][ks] = *(const short8*)(Kb + (size_t)(ms * 16 + lr) * S_ + ks * 32 + lg * 8);
  float rs[4] = {0.f, 0.f, 0.f, 0.f};
#pragma unroll 1
  for (int it = 0; it < 64; ++it) {
    int itn = (it < 63) ? it + 1 : it;
    int mn = itn * 64;
#pragma unroll
    for (int ms = 0; ms < 4; ms++)
#pragma unroll
      for (int ks = 0; ks < 2; ks++)
        kn[ms][ks] = *(const short8*)(Kb + (size_t)(mn + ms * 16 + lr) * S_ + ks * 32 + lg * 8);
#pragma unroll
    for (int ms = 0; ms < 4; ms++) {
      f32x4 e = {0.f, 0.f, 0.f, 0.f};
#pragma unroll
      for (int ks = 0; ks < 2; ks++)
        e = __builtin_amdgcn_mfma_f32_16x16x32_bf16(qf[ks], kc[ms][ks], e, 0, 0, 0);
#pragma unroll
      for (int r = 0; r < 4; r++) rs[r] += __builtin_amdgcn_exp2f(e[r]);
    }
#pragma unroll
    for (int ms = 0; ms < 4; ms++)
#pragma unroll
      for (int ks = 0; ks < 2; ks++) kc[ms][ks] = kn[ms][ks];
  }
#pragma unroll
  for (int off = 1; off < 16; off <<= 1)
#pragma unroll
    for (int r = 0; r < 4; r++) rs[r] += __shfl_xor(rs[r], off, 64);
  if (lr == 0) {
#pragma unroll
    for (int r = 0; r < 4; r++)
      inv_rse[(size_t)b * N_ + n0 + w * 16 + lg * 4 + r] = 1.f / rs[r];
  }
}

// K4: fused energy->att->PV per (b, 64-wide m tile). Software-pipelined, dbuf att,
// exp2 path, cvt_pk packing. Output xrp bf16 [b][m][c].
__global__ __launch_bounds__(256, 2) void k4_att(const short* __restrict__ Qt,
    const short* __restrict__ Kt, const short* __restrict__ Vp,
    const float* __restrict__ inv_rse, short* __restrict__ xrp) {
  int b = blockIdx.y, m0 = blockIdx.x * 64;
  int lane = threadIdx.x & 63, w = threadIdx.x >> 6;
  int lr = lane & 15, lg = lane >> 4;
  __shared__ short att[2][64][72];  // double-buffered [m][n] tile, 144B rows
  __shared__ float cs_red[4][64];
  const short* Qb = Qt + (size_t)b * N_ * S_;
  const short* Kb = Kt + (size_t)b * N_ * S_;
  const short* Vb = Vp + (size_t)b * 64 * (C_ * 64);
  const float* irb = inv_rse + (size_t)b * N_;
  short8 kfrag[4][2];
#pragma unroll
  for (int ms = 0; ms < 4; ms++)
#pragma unroll
    for (int ks = 0; ks < 2; ks++)
      kfrag[ms][ks] = *(const short8*)(Kb + (size_t)(m0 + ms * 16 + lr) * S_ + ks * 32 + lg * 8);
  f32x4 P[4][4];
#pragma unroll
  for (int i = 0; i < 4; i++)
#pragma unroll
    for (int j = 0; j < 4; j++) P[i][j] = {0.f, 0.f, 0.f, 0.f};
  float csum[4] = {0.f, 0.f, 0.f, 0.f};
  // prefetch iteration 0
  short8 qf[2], vf[2][4];
  float ir[4];
#pragma unroll
  for (int ks = 0; ks < 2; ks++)
    qf[ks] = *(const short8*)(Qb + (size_t)(w * 16 + lr) * S_ + ks * 32 + lg * 8);
#pragma unroll
  for (int ks = 0; ks < 2; ks++)
#pragma unroll
    for (int cs = 0; cs < 4; cs++)
      vf[ks][cs] = *(const short8*)(Vb + (size_t)(w * 64 + cs * 16 + lr) * 64 + ks * 32 + lg * 8);
#pragma unroll
  for (int r = 0; r < 4; r++) ir[r] = irb[w * 16 + lg * 4 + r];
  int buf = 0;
#pragma unroll 1
  for (int it = 0; it < 64; ++it) {
    // QK^T for this tile (registers only)
    f32x4 e[4];
#pragma unroll
    for (int ms = 0; ms < 4; ms++) e[ms] = {0.f, 0.f, 0.f, 0.f};
#pragma unroll
    for (int ms = 0; ms < 4; ms++)
#pragma unroll
      for (int ks = 0; ks < 2; ks++)
        e[ms] = __builtin_amdgcn_mfma_f32_16x16x32_bf16(qf[ks], kfrag[ms][ks], e[ms], 0, 0, 0);
    // issue next-iteration prefetch (lands during exp/pack/barrier/PV)
    int itn = (it < 63) ? it + 1 : it;
    int n2 = itn * 64;
    short8 qn[2], vn[2][4];
    float irn[4];
#pragma unroll
    for (int ks = 0; ks < 2; ks++)
      qn[ks] = *(const short8*)(Qb + (size_t)(n2 + w * 16 + lr) * S_ + ks * 32 + lg * 8);
#pragma unroll
    for (int ks = 0; ks < 2; ks++)
#pragma unroll
      for (int cs = 0; cs < 4; cs++)
        vn[ks][cs] = *(const short8*)(Vb + (size_t)itn * (C_ * 64) +
                                      (size_t)(w * 64 + cs * 16 + lr) * 64 + ks * 32 + lg * 8);
#pragma unroll
    for (int r = 0; r < 4; r++) irn[r] = irb[n2 + w * 16 + lg * 4 + r];
    // att = exp2(e) * inv_rse ; colsum ; pack to bf16 ; LDS write
#pragma unroll
    for (int ms = 0; ms < 4; ms++) {
      float a0 = __builtin_amdgcn_exp2f(e[ms][0]) * ir[0];
      float a1 = __builtin_amdgcn_exp2f(e[ms][1]) * ir[1];
      float a2 = __builtin_amdgcn_exp2f(e[ms][2]) * ir[2];
      float a3 = __builtin_amdgcn_exp2f(e[ms][3]) * ir[3];
      csum[ms] += (a0 + a1) + (a2 + a3);
      int2 pk;
      pk.x = cvtpk(a0, a1);
      pk.y = cvtpk(a2, a3);
      *(int2*)(&att[buf][ms * 16 + lr][w * 16 + lg * 4]) = pk;
    }
    __syncthreads();
    // PV with current V-frags
#pragma unroll
    for (int ks = 0; ks < 2; ks++) {
      short8 bfr[4];
#pragma unroll
      for (int ms = 0; ms < 4; ms++)
        bfr[ms] = *(const short8*)(&att[buf][ms * 16 + lr][ks * 32 + lg * 8]);
#pragma unroll
      for (int cs = 0; cs < 4; cs++)
#pragma unroll
        for (int ms = 0; ms < 4; ms++)
          P[cs][ms] = __builtin_amdgcn_mfma_f32_16x16x32_bf16(vf[ks][cs], bfr[ms], P[cs][ms], 0, 0, 0);
    }
    // rotate prefetch buffers
#pragma unroll
    for (int ks = 0; ks < 2; ks++) {
      qf[ks] = qn[ks];
#pragma unroll
      for (int cs = 0; cs < 4; cs++) vf[ks][cs] = vn[ks][cs];
    }
#pragma unroll
    for (int r = 0; r < 4; r++) ir[r] = irn[r];
    buf ^= 1;
  }
  // column-sum reduce (over n) then normalize P and store
#pragma unroll
  for (int off = 16; off < 64; off <<= 1)
#pragma unroll
    for (int ms = 0; ms < 4; ms++) csum[ms] += __shfl_xor(csum[ms], off, 64);
  if (lg == 0) {
#pragma unroll
    for (int ms = 0; ms < 4; ms++) cs_red[w][ms * 16 + lr] = csum[ms];
  }
  __syncthreads();
  float cinv[4];
#pragma unroll
  for (int ms = 0; ms < 4; ms++) {
    int m = ms * 16 + lr;
    cinv[ms] = 1.f / (1e-9f + cs_red[0][m] + cs_red[1][m] + cs_red[2][m] + cs_red[3][m]);
  }
  short* xb = xrp + ((size_t)b * N_ + m0) * C_;
#pragma unroll
  for (int cs = 0; cs < 4; cs++)
#pragma unroll
    for (int ms = 0; ms < 4; ms++) {
      int2 pk;
      pk.x = cvtpk(P[cs][ms][0] * cinv[ms], P[cs][ms][1] * cinv[ms]);
      pk.y = cvtpk(P[cs][ms][2] * cinv[ms], P[cs][ms][3] * cinv[ms]);
      *(int2*)(xb + (size_t)(ms * 16 + lr) * C_ + w * 64 + cs * 16 + lg * 4) = pk;
    }
}

// K5: out = x + relu(BN(W_t * x_r + b_t))
__global__ __launch_bounds__(256) void k5_out(const short* __restrict__ Wtb,
    const float* __restrict__ bt, const float* __restrict__ gamma,
    const float* __restrict__ beta, const float* __restrict__ mean,
    const float* __restrict__ var, const short* __restrict__ xrp,
    const float* __restrict__ x, float* __restrict__ out) {
  int b = blockIdx.y, m0 = blockIdx.x * 64;
  int lane = threadIdx.x & 63, w = threadIdx.x >> 6;
  int lr = lane & 15, lg = lane >> 4;
  f32x4 acc[4][4];
#pragma unroll
  for (int i = 0; i < 4; i++)
#pragma unroll
    for (int j = 0; j < 4; j++) acc[i][j] = {0.f, 0.f, 0.f, 0.f};
  const short* xrb = xrp + ((size_t)b * N_ + m0) * C_;
#pragma unroll 1
  for (int ks = 0; ks < 8; ks++) {
    int kb = ks * 32 + lg * 8;
    short8 bfr[4];
#pragma unroll
    for (int ms = 0; ms < 4; ms++)
      bfr[ms] = *(const short8*)(xrb + (size_t)(ms * 16 + lr) * C_ + kb);
#pragma unroll
    for (int os = 0; os < 4; os++) {
      short8 af = *(const short8*)(Wtb + (size_t)(w * 64 + os * 16 + lr) * C_ + kb);
#pragma unroll
      for (int ms = 0; ms < 4; ms++)
        acc[os][ms] = __builtin_amdgcn_mfma_f32_16x16x32_bf16(af, bfr[ms], acc[os][ms], 0, 0, 0);
    }
  }
  const float* xb = x + (size_t)b * C_ * N_ + m0;
  float* ob = out + (size_t)b * C_ * N_ + m0;
#pragma unroll
  for (int os = 0; os < 4; os++)
#pragma unroll
    for (int r = 0; r < 4; r++) {
      int o = w * 64 + os * 16 + lg * 4 + r;
      float bb = bt[o];
      float iv = gamma[o] * rsqrtf(var[o] + 1e-5f);
      float mn = mean[o], be = beta[o];
#pragma unroll
      for (int ms = 0; ms < 4; ms++) {
        int m = ms * 16 + lr;
        float v = (acc[os][ms][r] + bb - mn) * iv + be;
        v = fmaxf(v, 0.f);
        ob[(size_t)o * N_ + m] = xb[(size_t)o * N_ + m] + v;
      }
    }
}

extern "C" void kernel_launch(void* const* d_in, const int* in_sizes, int n_in,
                              void* d_out, int out_size, void* d_ws, size_t ws_size,
                              hipStream_t stream) {
  const float* x     = (const float*)d_in[0];
  const float* Wqk   = (const float*)d_in[1];
  const float* Wk2c  = (const float*)d_in[2];
  const float* Wv    = (const float*)d_in[3];
  const float* bv    = (const float*)d_in[4];
  const float* Wt    = (const float*)d_in[5];
  const float* bt    = (const float*)d_in[6];
  const float* gamma = (const float*)d_in[7];
  const float* beta  = (const float*)d_in[8];
  const float* mean  = (const float*)d_in[9];
  const float* var   = (const float*)d_in[10];
  const int*   idx   = (const int*)d_in[11];
  float* out = (float*)d_out;

  char* ws = (char*)d_ws;
  size_t off = 0;
  auto alloc = [&](size_t bytes) -> void* {
    void* p = ws + off;
    off = (off + bytes + 255) & ~(size_t)255;
    return p;
  };
  short* xt   = (short*)alloc((size_t)B_ * N_ * C_ * 2);
  short* Qt   = (short*)alloc((size_t)B_ * N_ * S_ * 2);
  short* Kt   = (short*)alloc((size_t)B_ * N_ * S_ * 2);
  short* Vp   = (short*)alloc((size_t)B_ * C_ * N_ * 2);
  float* irse = (float*)alloc((size_t)B_ * N_ * 4);
  short* xrp  = (short*)alloc((size_t)B_ * N_ * C_ * 2);
  short* Wvb  = (short*)alloc((size_t)C_ * C_ * 2);
  short* Wtb  = (short*)alloc((size_t)C_ * C_ * 2);

  kw_conv<<<dim3(64), 256, 0, stream>>>(Wv, Wt, Wvb, Wtb);
  k0_transpose<<<dim3(N_ / 64, C_ / 64, B_), 256, 0, stream>>>(x, xt);
  k1_qk<<<dim3(N_ / 64, B_), dim3(64, 4), 0, stream>>>(x, Wqk, Wk2c, idx, Qt, Kt);
  k2_xv<<<dim3(N_ / 64, B_), 256, 0, stream>>>(Wvb, bv, xt, Vp);
  k3_rse<<<dim3(N_ / 64, B_), 256, 0, stream>>>(Qt, Kt, irse);
  k4_att<<<dim3(N_ / 64, B_), 256, 0, stream>>>(Qt, Kt, Vp, irse, xrp);
  k5_out<<<dim3(N_ / 64, B_), 256, 0, stream>>>(Wtb, bt, gamma, beta, mean, var, xrp, x, out);
}